// Round 2
// baseline (390.760 us; speedup 1.0000x reference)
//
#include <hip/hip_runtime.h>

// HyperConnections fused kernel (fp32 I/O, fp32 math).
//
// out[t,:] = residual[t,:] * (SB + E*tanh(dotB*inv_rms)*beta_scale)
//          + x[t,:]        * (SA + E*sum_{i=1..E} tanh(dotA_i*inv_rms)*alpha_scale)
// where dotA_i = sum_d x[d]*w[d]*fnA[d][i], dotB = sum_d x[d]*w[d]*fnB[d],
//       inv_rms = rsqrt(mean(x^2)+eps),
//       SB = sum(static_beta), SA = sum_{i=1..E} sum_j static_alpha[j][i].
//
// Derivation: alpha.sum(axis=2)[...,1:].sum(-1) collapses to
// SA + E*sum_i dyn_alpha_i, and beta.sum(-1) to SB + E*dyn_beta, because
// dyn_alpha/dyn_beta are broadcast over the summed axes.

#define D_MODEL 2048
#define E_RATE 4
#define HC_EPS 1e-5f
#define NT 256
#define EPT 8  // elements per thread: 2048/256

extern "C" __global__ void __launch_bounds__(NT)
hc_kernel(const float* __restrict__ x,
          const float* __restrict__ resid,
          const float* __restrict__ w,
          const float* __restrict__ sA,     // [E, E+1] = [4,5]
          const float* __restrict__ sB,     // [E]
          const float* __restrict__ fnA,    // [D, E+1]
          const float* __restrict__ aScale, // [1]
          const float* __restrict__ fnB,    // [D]
          const float* __restrict__ bScale, // [1]
          float* __restrict__ out)
{
    const int tid = threadIdx.x;
    const size_t rowBase = (size_t)blockIdx.x * D_MODEL;

    // ---- vector loads: 8 fp32 = 32 B per thread (2x float4) ----
    const float4* xr = (const float4*)(x + rowBase);
    float4 x0 = xr[2 * tid], x1 = xr[2 * tid + 1];
    float4 w0 = ((const float4*)w)[2 * tid];
    float4 w1 = ((const float4*)w)[2 * tid + 1];
    float4 b0 = ((const float4*)fnB)[2 * tid];
    float4 b1 = ((const float4*)fnB)[2 * tid + 1];

    float xf[EPT]  = {x0.x, x0.y, x0.z, x0.w, x1.x, x1.y, x1.z, x1.w};
    float wf[EPT]  = {w0.x, w0.y, w0.z, w0.w, w1.x, w1.y, w1.z, w1.w};
    float fbf[EPT] = {b0.x, b0.y, b0.z, b0.w, b1.x, b1.y, b1.z, b1.w};

    float xwp[EPT];
#pragma unroll
    for (int d = 0; d < EPT; d++) xwp[d] = xf[d] * wf[d];

    // ---- accumulate 7 partials: da[0..4], db(5), ssq(6) ----
    float vals[7];
#pragma unroll
    for (int j = 0; j < 7; j++) vals[j] = 0.0f;

#pragma unroll
    for (int d = 0; d < EPT; d++) {
        vals[6] += xf[d] * xf[d];
        vals[5] += xwp[d] * fbf[d];
    }

    // fnA rows d0..d0+7 = 40 consecutive fp32 starting at tid*40 (160 B, 16B-aligned)
    const float4* fa4 = (const float4*)fnA;
#pragma unroll
    for (int j = 0; j < 10; j++) {
        float4 t4 = fa4[(size_t)tid * 10 + j];
        float fv[4] = {t4.x, t4.y, t4.z, t4.w};
#pragma unroll
        for (int q = 0; q < 4; q++) {
            const int e = j * 4 + q;  // flat index in [0,40)
            const int d = e / 5;      // compile-time constants after unroll
            const int i = e % 5;
            vals[i] += xwp[d] * fv[q];
        }
    }

    // ---- block reduction: wave-64 butterfly, then cross-wave via LDS ----
#pragma unroll
    for (int j = 0; j < 7; j++) {
        float v = vals[j];
        for (int off = 32; off > 0; off >>= 1) v += __shfl_xor(v, off, 64);
        vals[j] = v;
    }

    __shared__ float red[NT / 64][7];
    __shared__ float bc[2];
    const int wave = tid >> 6, lane = tid & 63;
    if (lane == 0) {
#pragma unroll
        for (int j = 0; j < 7; j++) red[wave][j] = vals[j];
    }
    __syncthreads();

    if (tid == 0) {
        float tot[7];
#pragma unroll
        for (int j = 0; j < 7; j++)
            tot[j] = red[0][j] + red[1][j] + red[2][j] + red[3][j];

        const float inv = rsqrtf(tot[6] * (1.0f / D_MODEL) + HC_EPS);
        const float asc = aScale[0];
        const float bsc = bScale[0];

        const float dynb = tanhf(tot[5] * inv) * bsc;
        float dyna_sum = 0.0f;
#pragma unroll
        for (int i = 1; i <= E_RATE; i++) dyna_sum += tanhf(tot[i] * inv) * asc;

        float SB = 0.0f;
#pragma unroll
        for (int e = 0; e < E_RATE; e++) SB += sB[e];
        float SA = 0.0f;
#pragma unroll
        for (int i = 1; i <= E_RATE; i++)
#pragma unroll
            for (int j = 0; j < E_RATE; j++) SA += sA[j * (E_RATE + 1) + i];

        bc[0] = SB + (float)E_RATE * dynb;      // residual coefficient
        bc[1] = SA + (float)E_RATE * dyna_sum;  // x coefficient
    }
    __syncthreads();

    const float cR = bc[0], cX = bc[1];

    // ---- epilogue: out = residual*cR + x*cX ----
    const float4* rr = (const float4*)(resid + rowBase);
    float4 r0 = rr[2 * tid], r1 = rr[2 * tid + 1];

    float4 o0, o1;
    o0.x = r0.x * cR + xf[0] * cX;
    o0.y = r0.y * cR + xf[1] * cX;
    o0.z = r0.z * cR + xf[2] * cX;
    o0.w = r0.w * cR + xf[3] * cX;
    o1.x = r1.x * cR + xf[4] * cX;
    o1.y = r1.y * cR + xf[5] * cX;
    o1.z = r1.z * cR + xf[6] * cX;
    o1.w = r1.w * cR + xf[7] * cX;

    float4* orow = (float4*)(out + rowBase);
    orow[2 * tid]     = o0;
    orow[2 * tid + 1] = o1;
}

extern "C" void kernel_launch(void* const* d_in, const int* in_sizes, int n_in,
                              void* d_out, int out_size, void* d_ws, size_t ws_size,
                              hipStream_t stream) {
    const float* x      = (const float*)d_in[0];
    const float* resid  = (const float*)d_in[1];
    const float* w      = (const float*)d_in[2];
    const float* sA     = (const float*)d_in[3];
    const float* sB     = (const float*)d_in[4];
    const float* fnA    = (const float*)d_in[5];
    const float* aScale = (const float*)d_in[6];
    const float* fnB    = (const float*)d_in[7];
    const float* bScale = (const float*)d_in[8];
    float* out          = (float*)d_out;

    const int n_tokens = in_sizes[0] / D_MODEL;  // B*T = 16384

    hc_kernel<<<n_tokens, NT, 0, stream>>>(x, resid, w, sA, sB, fnA, aScale,
                                           fnB, bScale, out);
}